// Round 1
// baseline (85.551 us; speedup 1.0000x reference)
//
#include <hip/hip_runtime.h>
#include <math.h>

#define N_GAUSS 512
#define H 256
#define W 256
#define TILE 16
#define TILES_W 16
#define TILES_H 16
#define GS_STRIDE 16   // floats per sorted-gaussian record

// Record layout (floats):
// 0:mx 1:my 2:ia 3:ibc 4:idd 5:opac 6:r 7:g 8:b 9:dep 10:txmin 11:txmax 12:tymin 13:tymax 14,15:pad

__global__ void gs_prep_kernel(const float* __restrict__ pos,
                               const float* __restrict__ scl,
                               const float* __restrict__ rot,
                               const float* __restrict__ col,
                               const float* __restrict__ opa,
                               const float* __restrict__ Km,
                               float* __restrict__ gs)
{
    __shared__ float s_depth[N_GAUSS];
    const int n = threadIdx.x;
    if (n >= N_GAUSS) return;

    // quaternion -> rotation
    float qw = rot[4*n+0], qx = rot[4*n+1], qy = rot[4*n+2], qz = rot[4*n+3];
    float qn = sqrtf(qw*qw + qx*qx + qy*qy + qz*qz);
    qw /= qn; qx /= qn; qy /= qn; qz /= qn;
    float R00 = 1.f - 2.f*(qy*qy + qz*qz);
    float R01 = 2.f*(qx*qy - qw*qz);
    float R02 = 2.f*(qx*qz + qw*qy);
    float R10 = 2.f*(qx*qy + qw*qz);
    float R11 = 1.f - 2.f*(qx*qx + qz*qz);
    float R12 = 2.f*(qy*qz - qw*qx);
    float R20 = 2.f*(qx*qz - qw*qy);
    float R21 = 2.f*(qy*qz + qw*qx);
    float R22 = 1.f - 2.f*(qx*qx + qy*qy);

    float s0 = scl[3*n+0], s1 = scl[3*n+1], s2 = scl[3*n+2];
    float M00 = R00*s0, M01 = R01*s1, M02 = R02*s2;
    float M10 = R10*s0, M11 = R11*s1, M12 = R12*s2;
    float M20 = R20*s0, M21 = R21*s1, M22 = R22*s2;

    // cov3 = M M^T (symmetric)
    float c00 = M00*M00 + M01*M01 + M02*M02;
    float c01 = M00*M10 + M01*M11 + M02*M12;
    float c02 = M00*M20 + M01*M21 + M02*M22;
    float c11 = M10*M10 + M11*M11 + M12*M12;
    float c12 = M10*M20 + M11*M21 + M12*M22;
    float c22 = M20*M20 + M21*M21 + M22*M22;

    float fx = Km[0], fy = Km[4], cx = Km[2], cy = Km[5];
    float X = pos[3*n+0], Y = pos[3*n+1], Z = pos[3*n+2];
    float mx = fx*X/Z + cx;
    float my = fy*Y/Z + cy;

    float j00 = fx/Z, j02 = -fx*X/(Z*Z);
    float j11 = fy/Z, j12 = -fy*Y/(Z*Z);

    // t = J * cov3  (J row0 = [j00,0,j02], row1 = [0,j11,j12])
    float t00 = j00*c00 + j02*c02;
    float t01 = j00*c01 + j02*c12;
    float t02 = j00*c02 + j02*c22;
    float t10 = j11*c01 + j12*c02;
    float t11 = j11*c11 + j12*c12;
    float t12 = j11*c12 + j12*c22;

    const float EPS = 1e-4f;
    float a  = t00*j00 + t02*j02 + EPS;
    float b  = t01*j11 + t02*j12;
    float c_ = t10*j00 + t12*j02;
    float d  = t11*j11 + t12*j12 + EPS;

    float trace = a + d;
    float det   = a*d - b*c_;
    float disc  = fmaxf(trace*trace - 4.f*det, 0.f);
    float lam   = 0.5f*(trace + sqrtf(disc));
    float radius = 3.0f * sqrtf(lam + 1e-6f);

    float txmin = fminf(fmaxf(floorf((mx - radius) / (float)TILE), 0.f), (float)(TILES_W-1));
    float txmax = fminf(fmaxf(ceilf ((mx + radius) / (float)TILE), 0.f), (float)(TILES_W-1));
    float tymin = fminf(fmaxf(floorf((my - radius) / (float)TILE), 0.f), (float)(TILES_H-1));
    float tymax = fminf(fmaxf(ceilf ((my + radius) / (float)TILE), 0.f), (float)(TILES_H-1));

    s_depth[n] = Z;
    __syncthreads();

    // stable rank for argsort(-depth): ascending by -Z, ties by index
    int rank = 0;
    #pragma unroll 8
    for (int j = 0; j < N_GAUSS; ++j) {
        float dj = s_depth[j];
        rank += (dj > Z) || (dj == Z && j < n);
    }

    float inv_det = 1.f / (a*d - b*c_);
    float ia  = d * inv_det;
    float ibc = -(b + c_) * inv_det;
    float idd = a * inv_det;

    float* o = gs + rank * GS_STRIDE;
    o[0]  = mx;
    o[1]  = my;
    o[2]  = ia;
    o[3]  = ibc;
    o[4]  = idd;
    o[5]  = opa[n];
    o[6]  = col[3*n+0];
    o[7]  = col[3*n+1];
    o[8]  = col[3*n+2];
    o[9]  = Z;
    o[10] = txmin;
    o[11] = txmax;
    o[12] = tymin;
    o[13] = tymax;
    o[14] = 0.f;
    o[15] = 0.f;
}

__global__ __launch_bounds__(256) void gs_render_kernel(const float* __restrict__ gs,
                                                        const float* __restrict__ bg,
                                                        float* __restrict__ out)
{
    __shared__ float s[N_GAUSS * GS_STRIDE];   // 32 KB

    const int tile = blockIdx.x;           // 0..255
    const int tx = tile & (TILES_W - 1);
    const int ty = tile >> 4;
    const int t  = threadIdx.x;            // 0..255

    // stage whole sorted table into LDS (8192 floats = 2048 float4)
    const float4* gsrc = (const float4*)gs;
    float4* sdst = (float4*)s;
    #pragma unroll
    for (int i = 0; i < (N_GAUSS * GS_STRIDE / 4) / 256; ++i) {
        sdst[t + i * 256] = gsrc[t + i * 256];
    }
    __syncthreads();

    const int px = tx * TILE + (t & 15);
    const int py = ty * TILE + (t >> 4);
    const float fpx = (float)px;
    const float fpy = (float)py;
    const float ptx = (float)tx;
    const float pty = (float)ty;

    float T = 1.f;
    float accr = 0.f, accg = 0.f, accb = 0.f, accd = 0.f, acca = 0.f;

    for (int n = 0; n < N_GAUSS; ++n) {
        const float* g = s + n * GS_STRIDE;
        // block-uniform tile-visibility cull
        if (ptx < g[10] || ptx > g[11] || pty < g[12] || pty > g[13]) continue;

        float dx = fpx - g[0];
        float dy = fpy - g[1];
        float mahal = g[2]*dx*dx + g[3]*dx*dy + g[4]*dy*dy;
        float w = __expf(-0.5f * mahal) * g[5];
        if (w > 0.01f) {
            float cw = T * w;
            accr += cw * g[6];
            accg += cw * g[7];
            accb += cw * g[8];
            accd += cw * g[9];
            acca += cw;
            T *= (1.f - w);
        }
    }

    float b0 = bg[0], b1 = bg[1], b2 = bg[2];
    const int pidx = py * W + px;
    out[pidx*3 + 0] = fminf(fmaxf(b0 + accr, 0.f), 1.f);
    out[pidx*3 + 1] = fminf(fmaxf(b1 + accg, 0.f), 1.f);
    out[pidx*3 + 2] = fminf(fmaxf(b2 + accb, 0.f), 1.f);
    out[H*W*3 + pidx] = accd;
    out[H*W*3 + H*W + pidx] = acca;
}

extern "C" void kernel_launch(void* const* d_in, const int* in_sizes, int n_in,
                              void* d_out, int out_size, void* d_ws, size_t ws_size,
                              hipStream_t stream) {
    const float* positions = (const float*)d_in[0];
    const float* scales    = (const float*)d_in[1];
    const float* rotations = (const float*)d_in[2];
    const float* colors    = (const float*)d_in[3];
    const float* opacities = (const float*)d_in[4];
    const float* Km        = (const float*)d_in[5];
    const float* background= (const float*)d_in[6];
    float* out = (float*)d_out;
    float* gs  = (float*)d_ws;   // 512 * 16 floats = 32 KB

    gs_prep_kernel<<<1, N_GAUSS, 0, stream>>>(positions, scales, rotations,
                                              colors, opacities, Km, gs);
    gs_render_kernel<<<TILES_W * TILES_H, 256, 0, stream>>>(gs, background, out);
}

// Round 2
// 16.789 us; speedup vs baseline: 5.0957x; 5.0957x over previous
//
#include <hip/hip_runtime.h>
#include <math.h>

#define N_GAUSS 512
#define H 256
#define W 256
#define TILE 16
#define TILES_W 16
#define TILES_H 16
#define REC 12        // floats per record: mx,my,ia,ibc,idd,op,r,g,b,dep,pad,pad
#define NSEG 4
#define CB_STRIDE 25  // 4 seg * 6 floats = 24, pad to 25 (coprime w/ 32 banks)

__global__ __launch_bounds__(1024) void gs_fused_kernel(
    const float* __restrict__ pos,
    const float* __restrict__ scl,
    const float* __restrict__ rot,
    const float* __restrict__ col,
    const float* __restrict__ opa,
    const float* __restrict__ Km,
    const float* __restrict__ bg,
    float* __restrict__ out)
{
    __shared__ float rec[N_GAUSS * REC];   // 24 KB
    __shared__ float cd[N_GAUSS];          // 2 KB   compacted depths
    __shared__ int   ci[N_GAUSS];          // 2 KB   compacted orig indices
    __shared__ int   sl[N_GAUSS];          // 2 KB   depth-sorted index list
    __shared__ int   wcnt[16];
    __shared__ float cbuf[256 * CB_STRIDE]; // 25.6 KB per-segment partials

    const int t    = threadIdx.x;
    const int tile = blockIdx.x;
    const int tx   = tile & (TILES_W - 1);
    const int ty   = tile >> 4;

    // ---------------- Phase A: per-gaussian projection (threads 0..511) -----
    bool  pred = false;
    float dep  = 0.f;
    if (t < N_GAUSS) {
        const int n = t;
        float qw = rot[4*n+0], qx = rot[4*n+1], qy = rot[4*n+2], qz = rot[4*n+3];
        float qn = sqrtf(qw*qw + qx*qx + qy*qy + qz*qz);
        qw /= qn; qx /= qn; qy /= qn; qz /= qn;
        float R00 = 1.f - 2.f*(qy*qy + qz*qz);
        float R01 = 2.f*(qx*qy - qw*qz);
        float R02 = 2.f*(qx*qz + qw*qy);
        float R10 = 2.f*(qx*qy + qw*qz);
        float R11 = 1.f - 2.f*(qx*qx + qz*qz);
        float R12 = 2.f*(qy*qz - qw*qx);
        float R20 = 2.f*(qx*qz - qw*qy);
        float R21 = 2.f*(qy*qz + qw*qx);
        float R22 = 1.f - 2.f*(qx*qx + qy*qy);

        float s0 = scl[3*n+0], s1 = scl[3*n+1], s2 = scl[3*n+2];
        float M00 = R00*s0, M01 = R01*s1, M02 = R02*s2;
        float M10 = R10*s0, M11 = R11*s1, M12 = R12*s2;
        float M20 = R20*s0, M21 = R21*s1, M22 = R22*s2;

        float c00 = M00*M00 + M01*M01 + M02*M02;
        float c01 = M00*M10 + M01*M11 + M02*M12;
        float c02 = M00*M20 + M01*M21 + M02*M22;
        float c11 = M10*M10 + M11*M11 + M12*M12;
        float c12 = M10*M20 + M11*M21 + M12*M22;
        float c22 = M20*M20 + M21*M21 + M22*M22;

        float fx = Km[0], fy = Km[4], cx = Km[2], cy = Km[5];
        float X = pos[3*n+0], Y = pos[3*n+1], Z = pos[3*n+2];
        float mx = fx*X/Z + cx;
        float my = fy*Y/Z + cy;

        float j00 = fx/Z, j02 = -fx*X/(Z*Z);
        float j11 = fy/Z, j12 = -fy*Y/(Z*Z);

        float t00 = j00*c00 + j02*c02;
        float t01 = j00*c01 + j02*c12;
        float t02 = j00*c02 + j02*c22;
        float t10 = j11*c01 + j12*c02;
        float t11 = j11*c11 + j12*c12;
        float t12 = j11*c12 + j12*c22;

        const float EPS = 1e-4f;
        float a  = t00*j00 + t02*j02 + EPS;
        float b  = t01*j11 + t02*j12;
        float c_ = t10*j00 + t12*j02;
        float d  = t11*j11 + t12*j12 + EPS;

        float trace = a + d;
        float det   = a*d - b*c_;
        float disc  = fmaxf(trace*trace - 4.f*det, 0.f);
        float lam   = 0.5f*(trace + sqrtf(disc));
        float radius = 3.0f * sqrtf(lam + 1e-6f);

        float txmin = fminf(fmaxf(floorf((mx - radius) / (float)TILE), 0.f), (float)(TILES_W-1));
        float txmax = fminf(fmaxf(ceilf ((mx + radius) / (float)TILE), 0.f), (float)(TILES_W-1));
        float tymin = fminf(fmaxf(floorf((my - radius) / (float)TILE), 0.f), (float)(TILES_H-1));
        float tymax = fminf(fmaxf(ceilf ((my + radius) / (float)TILE), 0.f), (float)(TILES_H-1));

        float inv_det = 1.f / (a*d - b*c_);

        float* o = rec + n * REC;
        o[0]  = mx;
        o[1]  = my;
        o[2]  = d * inv_det;            // ia
        o[3]  = -(b + c_) * inv_det;    // ib + ic
        o[4]  = a * inv_det;            // id
        o[5]  = opa[n];
        o[6]  = col[3*n+0];
        o[7]  = col[3*n+1];
        o[8]  = col[3*n+2];
        o[9]  = Z;
        o[10] = 0.f;
        o[11] = 0.f;

        dep = Z;
        float ftx = (float)tx, fty = (float)ty;
        pred = (ftx >= txmin) && (ftx <= txmax) && (fty >= tymin) && (fty <= tymax);
    }

    // ---------------- Phase B: ballot compaction (order-preserving) ---------
    unsigned long long m = __ballot(pred);
    const int wave = t >> 6;
    const int lane = t & 63;
    if (lane == 0) wcnt[wave] = __popcll(m);
    __syncthreads();

    int base = 0, K = 0;
    #pragma unroll
    for (int w = 0; w < 16; ++w) {
        int c = wcnt[w];
        if (w < wave) base += c;
        K += c;
    }
    if (pred) {
        int p = base + __popcll(m & ((1ULL << lane) - 1ULL));
        cd[p] = dep;
        ci[p] = t;
    }
    __syncthreads();

    // ---------------- Phase C: stable rank-sort by depth descending ---------
    if (t < K) {
        float dme = cd[t];
        int   ime = ci[t];
        int   r = 0;
        for (int j = 0; j < K; ++j) {
            float dj = cd[j];
            int   ij = ci[j];
            r += (dj > dme) || (dj == dme && ij < ime);
        }
        sl[r] = ime;
    }
    __syncthreads();

    // ---------------- Phase D: segmented composite --------------------------
    const int seg = t >> 8;        // 0..3
    const int p   = t & 255;       // pixel within tile
    const int len = (K + NSEG - 1) >> 2;
    const int s0  = seg * len;
    const int s1  = min(s0 + len, K);

    const int px = tx * TILE + (p & 15);
    const int py = ty * TILE + (p >> 4);
    const float fpx = (float)px;
    const float fpy = (float)py;

    float T = 1.f;
    float ar = 0.f, ag = 0.f, ab = 0.f, ad = 0.f, aa = 0.f;

    for (int n = s0; n < s1; ++n) {
        const int idx = sl[n];
        const float* g = rec + idx * REC;
        float4 g0 = *(const float4*)(g);      // mx, my, ia, ibc
        float4 g1 = *(const float4*)(g + 4);  // idd, op, r, g
        float4 g2 = *(const float4*)(g + 8);  // b, dep, pad, pad

        float dx = fpx - g0.x;
        float dy = fpy - g0.y;
        float mah = g0.z*dx*dx + g0.w*dx*dy + g1.x*dy*dy;
        float w = __expf(-0.5f * mah) * g1.y;
        if (w > 0.01f) {
            float cw = T * w;
            ar += cw * g1.z;
            ag += cw * g1.w;
            ab += cw * g2.x;
            ad += cw * g2.y;
            aa += cw;
            T *= (1.f - w);
        }
    }

    {
        float* cb = cbuf + p * CB_STRIDE + seg * 6;
        cb[0] = ar; cb[1] = ag; cb[2] = ab; cb[3] = ad; cb[4] = aa; cb[5] = T;
    }
    __syncthreads();

    // ---------------- Phase E: in-order combine + store (threads 0..255) ----
    if (t < 256) {
        const float* cb = cbuf + t * CB_STRIDE;
        float Tc = 1.f;
        float r_ = 0.f, g_ = 0.f, b_ = 0.f, d_ = 0.f, a_ = 0.f;
        #pragma unroll
        for (int s = 0; s < NSEG; ++s) {
            r_ += Tc * cb[s*6 + 0];
            g_ += Tc * cb[s*6 + 1];
            b_ += Tc * cb[s*6 + 2];
            d_ += Tc * cb[s*6 + 3];
            a_ += Tc * cb[s*6 + 4];
            Tc *= cb[s*6 + 5];
        }
        const int qx = tx * TILE + (t & 15);
        const int qy = ty * TILE + (t >> 4);
        const int pidx = qy * W + qx;
        float b0 = bg[0], b1 = bg[1], b2 = bg[2];
        out[pidx*3 + 0] = fminf(fmaxf(b0 + r_, 0.f), 1.f);
        out[pidx*3 + 1] = fminf(fmaxf(b1 + g_, 0.f), 1.f);
        out[pidx*3 + 2] = fminf(fmaxf(b2 + b_, 0.f), 1.f);
        out[H*W*3 + pidx] = d_;
        out[H*W*3 + H*W + pidx] = a_;
    }
}

extern "C" void kernel_launch(void* const* d_in, const int* in_sizes, int n_in,
                              void* d_out, int out_size, void* d_ws, size_t ws_size,
                              hipStream_t stream) {
    const float* positions  = (const float*)d_in[0];
    const float* scales     = (const float*)d_in[1];
    const float* rotations  = (const float*)d_in[2];
    const float* colors     = (const float*)d_in[3];
    const float* opacities  = (const float*)d_in[4];
    const float* Km         = (const float*)d_in[5];
    const float* background = (const float*)d_in[6];
    float* out = (float*)d_out;

    gs_fused_kernel<<<TILES_W * TILES_H, 1024, 0, stream>>>(
        positions, scales, rotations, colors, opacities, Km, background, out);
}

// Round 3
// 11.310 us; speedup vs baseline: 7.5640x; 1.4844x over previous
//
#include <hip/hip_runtime.h>
#include <math.h>

#define N_GAUSS 512
#define H 256
#define W 256
#define TILE 16
#define TILES_W 16
#define TILES_H 16
#define NSEG 4
#define CB_STRIDE 25  // 4 seg * 6 floats = 24, pad to 25 (conflict-free combine)

// Sorted-compact record: 3 float4 per gaussian
//  f0 = {mx, my, -0.5*ia, -0.5*(ib+ic)}
//  f1 = {-0.5*id, opac, colR, colG}
//  f2 = {colB, depth, 0, 0}

__global__ __launch_bounds__(1024) void gs_fused_kernel(
    const float* __restrict__ pos,
    const float* __restrict__ scl,
    const float* __restrict__ rot,
    const float* __restrict__ col,
    const float* __restrict__ opa,
    const float* __restrict__ Km,
    const float* __restrict__ bg,
    float* __restrict__ out)
{
    __shared__ float4 rec[N_GAUSS * 3];              // 24 KB sorted-compact records
    __shared__ unsigned long long ckey[N_GAUSS];     // 4 KB compacted sort keys
    __shared__ int wcnt[16];
    __shared__ float cbuf[256 * CB_STRIDE];          // 25.6 KB per-segment partials

    const int t    = threadIdx.x;
    const int tile = blockIdx.x;
    const int tx   = tile & (TILES_W - 1);
    const int ty   = tile >> 4;

    // ---------------- Phase A: projection, record kept in registers --------
    bool pred = false;
    unsigned long long key = 0;
    float4 f0, f1, f2;

    if (t < N_GAUSS) {
        const int n = t;
        float4 q = ((const float4*)rot)[n];
        float qq = q.x*q.x + q.y*q.y + q.z*q.z + q.w*q.w;
        float rq = __builtin_amdgcn_rsqf(qq);
        float qw = q.x*rq, qx = q.y*rq, qy = q.z*rq, qz = q.w*rq;

        float R00 = 1.f - 2.f*(qy*qy + qz*qz);
        float R01 = 2.f*(qx*qy - qw*qz);
        float R02 = 2.f*(qx*qz + qw*qy);
        float R10 = 2.f*(qx*qy + qw*qz);
        float R11 = 1.f - 2.f*(qx*qx + qz*qz);
        float R12 = 2.f*(qy*qz - qw*qx);
        float R20 = 2.f*(qx*qz - qw*qy);
        float R21 = 2.f*(qy*qz + qw*qx);
        float R22 = 1.f - 2.f*(qx*qx + qy*qy);

        float s0 = scl[3*n+0], s1 = scl[3*n+1], s2 = scl[3*n+2];
        float M00 = R00*s0, M01 = R01*s1, M02 = R02*s2;
        float M10 = R10*s0, M11 = R11*s1, M12 = R12*s2;
        float M20 = R20*s0, M21 = R21*s1, M22 = R22*s2;

        float c00 = M00*M00 + M01*M01 + M02*M02;
        float c01 = M00*M10 + M01*M11 + M02*M12;
        float c02 = M00*M20 + M01*M21 + M02*M22;
        float c11 = M10*M10 + M11*M11 + M12*M12;
        float c12 = M10*M20 + M11*M21 + M12*M22;
        float c22 = M20*M20 + M21*M21 + M22*M22;

        float fx = Km[0], fy = Km[4], cx = Km[2], cy = Km[5];
        float X = pos[3*n+0], Y = pos[3*n+1], Z = pos[3*n+2];
        float rz = __builtin_amdgcn_rcpf(Z);
        float mx = fx*X*rz + cx;
        float my = fy*Y*rz + cy;

        float j00 = fx*rz,  j02 = -fx*X*rz*rz;
        float j11 = fy*rz,  j12 = -fy*Y*rz*rz;

        float t00 = j00*c00 + j02*c02;
        float t01 = j00*c01 + j02*c12;
        float t02 = j00*c02 + j02*c22;
        float t10 = j11*c01 + j12*c02;
        float t11 = j11*c11 + j12*c12;
        float t12 = j11*c12 + j12*c22;

        const float EPS = 1e-4f;
        float a  = t00*j00 + t02*j02 + EPS;
        float b  = t01*j11 + t02*j12;
        float c_ = t10*j00 + t12*j02;
        float d  = t11*j11 + t12*j12 + EPS;

        float trace = a + d;
        float det   = a*d - b*c_;
        float disc  = fmaxf(trace*trace - 4.f*det, 0.f);
        float lam   = 0.5f*(trace + sqrtf(disc));
        float radius = 3.0f * sqrtf(lam + 1e-6f);

        float txmin = fminf(fmaxf(floorf((mx - radius) * (1.f/TILE)), 0.f), (float)(TILES_W-1));
        float txmax = fminf(fmaxf(ceilf ((mx + radius) * (1.f/TILE)), 0.f), (float)(TILES_W-1));
        float tymin = fminf(fmaxf(floorf((my - radius) * (1.f/TILE)), 0.f), (float)(TILES_H-1));
        float tymax = fminf(fmaxf(ceilf ((my + radius) * (1.f/TILE)), 0.f), (float)(TILES_H-1));

        float inv_det = __builtin_amdgcn_rcpf(det);
        float ia  = d * inv_det;
        float ibc = -(b + c_) * inv_det;
        float idd = a * inv_det;

        f0 = make_float4(mx, my, -0.5f*ia, -0.5f*ibc);
        f1 = make_float4(-0.5f*idd, opa[n], col[3*n+0], col[3*n+1]);
        f2 = make_float4(col[3*n+2], Z, 0.f, 0.f);

        // descending-depth stable key: larger key sorts first
        unsigned fb = __float_as_uint(Z);   // Z > 0 -> bit pattern monotone
        key = ((unsigned long long)fb << 32) | (unsigned)(N_GAUSS - 1 - n);

        float ftx = (float)tx, fty = (float)ty;
        pred = (ftx >= txmin) && (ftx <= txmax) && (fty >= tymin) && (fty <= tymax);
    }

    // ---------------- Phase B: ballot-compact the sort keys ----------------
    unsigned long long m = __ballot(pred);
    const int wave = t >> 6;
    const int lane = t & 63;
    if (lane == 0) wcnt[wave] = __popcll(m);
    __syncthreads();

    int base = 0, K = 0;
    #pragma unroll
    for (int w = 0; w < 16; ++w) {
        int c = wcnt[w];
        if (w < wave) base += c;
        K += c;
    }
    if (pred) {
        int p = base + __popcll(m & ((1ULL << lane) - 1ULL));
        ckey[p] = key;
    }
    __syncthreads();

    // ---------------- Phase C: rank + scatter register record sorted -------
    if (pred) {
        int r = 0;
        for (int j = 0; j < K; ++j) r += (ckey[j] > key);
        rec[r*3 + 0] = f0;
        rec[r*3 + 1] = f1;
        rec[r*3 + 2] = f2;
    }
    __syncthreads();

    // ---------------- Phase D: segmented composite, sequential records -----
    const int seg = t >> 8;        // 0..3
    const int p   = t & 255;       // pixel within tile
    const int len = (K + NSEG - 1) >> 2;
    const int s0  = seg * len;
    const int s1  = min(s0 + len, K);

    const float fpx = (float)(tx * TILE + (p & 15));
    const float fpy = (float)(ty * TILE + (p >> 4));

    float T = 1.f;
    float ar = 0.f, ag = 0.f, ab = 0.f, ad = 0.f, aa = 0.f;

    #pragma unroll 4
    for (int n = s0; n < s1; ++n) {
        float4 g0 = rec[n*3 + 0];
        float4 g1 = rec[n*3 + 1];
        float4 g2 = rec[n*3 + 2];
        float dx = fpx - g0.x;
        float dy = fpy - g0.y;
        float e  = g0.z*dx*dx + g0.w*dx*dy + g1.x*dy*dy;   // = -0.5*mahal
        float w  = __expf(e) * g1.y;
        if (w > 0.01f) {
            float cw = T * w;
            ar += cw * g1.z;
            ag += cw * g1.w;
            ab += cw * g2.x;
            ad += cw * g2.y;
            aa += cw;
            T *= (1.f - w);
        }
    }

    {
        float* cb = cbuf + p * CB_STRIDE + seg * 6;
        cb[0] = ar; cb[1] = ag; cb[2] = ab; cb[3] = ad; cb[4] = aa; cb[5] = T;
    }
    __syncthreads();

    // ---------------- Phase E: in-order combine + store (threads 0..255) ---
    if (t < 256) {
        const float* cb = cbuf + t * CB_STRIDE;
        float Tc = 1.f;
        float r_ = 0.f, g_ = 0.f, b_ = 0.f, d_ = 0.f, a_ = 0.f;
        #pragma unroll
        for (int s = 0; s < NSEG; ++s) {
            r_ += Tc * cb[s*6 + 0];
            g_ += Tc * cb[s*6 + 1];
            b_ += Tc * cb[s*6 + 2];
            d_ += Tc * cb[s*6 + 3];
            a_ += Tc * cb[s*6 + 4];
            Tc *= cb[s*6 + 5];
        }
        const int qx = tx * TILE + (t & 15);
        const int qy = ty * TILE + (t >> 4);
        const int pidx = qy * W + qx;
        float b0 = bg[0], b1 = bg[1], b2 = bg[2];
        out[pidx*3 + 0] = fminf(fmaxf(b0 + r_, 0.f), 1.f);
        out[pidx*3 + 1] = fminf(fmaxf(b1 + g_, 0.f), 1.f);
        out[pidx*3 + 2] = fminf(fmaxf(b2 + b_, 0.f), 1.f);
        out[H*W*3 + pidx] = d_;
        out[H*W*3 + H*W + pidx] = a_;
    }
}

extern "C" void kernel_launch(void* const* d_in, const int* in_sizes, int n_in,
                              void* d_out, int out_size, void* d_ws, size_t ws_size,
                              hipStream_t stream) {
    const float* positions  = (const float*)d_in[0];
    const float* scales     = (const float*)d_in[1];
    const float* rotations  = (const float*)d_in[2];
    const float* colors     = (const float*)d_in[3];
    const float* opacities  = (const float*)d_in[4];
    const float* Km         = (const float*)d_in[5];
    const float* background = (const float*)d_in[6];
    float* out = (float*)d_out;

    gs_fused_kernel<<<TILES_W * TILES_H, 1024, 0, stream>>>(
        positions, scales, rotations, colors, opacities, Km, background, out);
}